// Round 2
// baseline (223.202 us; speedup 1.0000x reference)
//
#include <hip/hip_runtime.h>
#include <hip/hip_bf16.h>
#include <math.h>

// Problem constants (match reference)
#define GN    16384      // nodes
#define HID   128
#define MAXD  48
#define BN_SCALE 0.9999950000374998f   // 1/sqrt(1+1e-5) rounded to f32

// ---------------------------------------------------------------------------
// Adjacency build: dense [N][MAXD] source lists + fill counts (incl self loop)
// ---------------------------------------------------------------------------
__global__ __launch_bounds__(256) void k_init(int* __restrict__ adj,
                                              int* __restrict__ fill) {
    int v = blockIdx.x * 256 + threadIdx.x;
    if (v < GN) {
        fill[v] = 1;              // self loop occupies slot 0
        adj[v * MAXD] = v;
    }
}

__global__ __launch_bounds__(256) void k_build(const int* __restrict__ src,
                                               const int* __restrict__ dst,
                                               int* __restrict__ adj,
                                               int* __restrict__ fill, int E) {
    int e = blockIdx.x * 256 + threadIdx.x;
    if (e < E) {
        int dv = dst[e];
        int slot = atomicAdd(&fill[dv], 1);
        if (slot < MAXD) adj[dv * MAXD + slot] = src[e];   // drop overflow (ref: mode='drop')
    }
}

// ---------------------------------------------------------------------------
// Dual fp32 GEMM: Cl = X@Wl + bl, Cr = X@Wr + br.  X:[N,128] W:[128,128]
// Block: 64 rows x full 128 cols, 256 threads, micro-tile 8 rows x 4 cols x 2.
// ---------------------------------------------------------------------------
__global__ __launch_bounds__(256) void k_gemm_dual(
    const float* __restrict__ X,
    const float* __restrict__ Wl, const float* __restrict__ bl,
    const float* __restrict__ Wr, const float* __restrict__ br,
    float* __restrict__ Cl, float* __restrict__ Cr)
{
    __shared__ float xs[128][68];    // transposed x tile: xs[k][m], padded (16B-aligned rows)
    __shared__ float wls[32][128];
    __shared__ float wrs[32][128];

    const int tid  = threadIdx.x;
    const int row0 = blockIdx.x * 64;

    // Stage X tile transposed (coalesced float4 global reads)
    {
        int m  = tid >> 5;            // 0..7
        int k4 = tid & 31;            // float4 index along k
        const float4* Xp = reinterpret_cast<const float4*>(X + (size_t)row0 * 128);
        #pragma unroll
        for (int rr = 0; rr < 8; ++rr) {
            int mm = m + rr * 8;
            float4 v = Xp[(size_t)mm * 32 + k4];
            int k0 = k4 * 4;
            xs[k0 + 0][mm] = v.x; xs[k0 + 1][mm] = v.y;
            xs[k0 + 2][mm] = v.z; xs[k0 + 3][mm] = v.w;
        }
    }

    const int tn = tid & 31;   // cols tn*4 .. tn*4+3
    const int tm = tid >> 5;   // rows tm*8 .. tm*8+7
    float accl[8][4] = {{0.f}};
    float accr[8][4] = {{0.f}};

    for (int kb = 0; kb < 4; ++kb) {
        __syncthreads();
        // stage 32x128 W chunks
        {
            int kk = tid >> 5;            // 0..7
            int n0 = (tid & 31) * 4;
            #pragma unroll
            for (int rr = 0; rr < 4; ++rr) {
                int krow = kk + rr * 8;
                int gk   = kb * 32 + krow;
                *reinterpret_cast<float4*>(&wls[krow][n0]) =
                    *reinterpret_cast<const float4*>(&Wl[gk * 128 + n0]);
                *reinterpret_cast<float4*>(&wrs[krow][n0]) =
                    *reinterpret_cast<const float4*>(&Wr[gk * 128 + n0]);
            }
        }
        __syncthreads();
        #pragma unroll
        for (int kk = 0; kk < 32; ++kk) {
            int k = kb * 32 + kk;
            float4 xa  = *reinterpret_cast<const float4*>(&xs[k][tm * 8]);
            float4 xb  = *reinterpret_cast<const float4*>(&xs[k][tm * 8 + 4]);
            float4 wl4 = *reinterpret_cast<const float4*>(&wls[kk][tn * 4]);
            float4 wr4 = *reinterpret_cast<const float4*>(&wrs[kk][tn * 4]);
            float xr[8]  = {xa.x, xa.y, xa.z, xa.w, xb.x, xb.y, xb.z, xb.w};
            float wlr[4] = {wl4.x, wl4.y, wl4.z, wl4.w};
            float wrr[4] = {wr4.x, wr4.y, wr4.z, wr4.w};
            #pragma unroll
            for (int r = 0; r < 8; ++r)
                #pragma unroll
                for (int c = 0; c < 4; ++c) {
                    accl[r][c] = fmaf(xr[r], wlr[c], accl[r][c]);
                    accr[r][c] = fmaf(xr[r], wrr[c], accr[r][c]);
                }
        }
    }

    float4 blv = *reinterpret_cast<const float4*>(&bl[tn * 4]);
    float4 brv = *reinterpret_cast<const float4*>(&br[tn * 4]);
    #pragma unroll
    for (int r = 0; r < 8; ++r) {
        int row = row0 + tm * 8 + r;
        float4 o;
        o.x = accl[r][0] + blv.x; o.y = accl[r][1] + blv.y;
        o.z = accl[r][2] + blv.z; o.w = accl[r][3] + blv.w;
        *reinterpret_cast<float4*>(&Cl[(size_t)row * 128 + tn * 4]) = o;
        o.x = accr[r][0] + brv.x; o.y = accr[r][1] + brv.y;
        o.z = accr[r][2] + brv.z; o.w = accr[r][3] + brv.w;
        *reinterpret_cast<float4*>(&Cr[(size_t)row * 128 + tn * 4]) = o;
    }
}

// ---------------------------------------------------------------------------
// Trimmed-mean aggregation (128 features). One node per block, f = threadIdx.
// out = [relu_bn ? relu(bn(...)) : ...](trim_agg(hl) + hr)
// ---------------------------------------------------------------------------
__global__ __launch_bounds__(128) void k_agg(
    const float* __restrict__ hl, const float* __restrict__ hr,
    const int* __restrict__ adj, const int* __restrict__ fill,
    const float* __restrict__ g, const float* __restrict__ be,
    float* __restrict__ out, int do_bnrelu)
{
    const int v = blockIdx.x;
    const int f = threadIdx.x;
    __shared__ int sadj[MAXD];

    const int cnt = fill[v];
    const int d   = min(cnt, MAXD);
    if (f < d) sadj[f] = adj[v * MAXD + f] * 128;   // prescale to row offset
    __syncthreads();

    float total = 0.f;
    float s0 = INFINITY, s1 = INFINITY, s2 = INFINITY, s3 = INFINITY;
    float l0 = -INFINITY, l1 = -INFINITY, l2 = -INFINITY, l3 = -INFINITY;

    if (cnt < 20) {   // t == 1: only need min & max (wave-uniform branch)
        for (int i = 0; i < d; ++i) {
            float x = hl[sadj[i] + f];
            total += x;
            s0 = fminf(s0, x);
            l0 = fmaxf(l0, x);
        }
    } else {          // t in [2,4]: track 4 smallest + 4 largest (branchless insert)
        for (int i = 0; i < d; ++i) {
            float x = hl[sadj[i] + f];
            total += x;
            float a = x;
            float t0 = fminf(s0, a); a = fmaxf(s0, a); s0 = t0;
            float t1 = fminf(s1, a); a = fmaxf(s1, a); s1 = t1;
            float t2 = fminf(s2, a); a = fmaxf(s2, a); s2 = t2;
            s3 = fminf(s3, a);
            float b = x;
            float u0 = fmaxf(l0, b); b = fminf(l0, b); l0 = u0;
            float u1 = fmaxf(l1, b); b = fminf(l1, b); l1 = u1;
            float u2 = fmaxf(l2, b); b = fminf(l2, b); l2 = u2;
            l3 = fmaxf(l3, b);
        }
    }

    int t = (int)floorf((float)cnt * 0.1f);
    if (t < 1) t = 1;
    int tcnt = cnt - 2 * t;
    bool use_trim = (cnt >= 5) && (tcnt > 0);
    float dd = (float)cnt;
    float res;
    if (use_trim) {
        int tt = min(t, 4);
        float bot = s0, top = l0;
        if (tt > 1) { bot += s1; top += l1; }
        if (tt > 2) { bot += s2; top += l2; }
        if (tt > 3) { bot += s3; top += l3; }
        res = (total - bot - top) / (dd * (float)tcnt);
    } else {
        res = total / (dd * dd);
    }

    float val = res + hr[v * 128 + f];
    if (do_bnrelu) {
        val = val * (BN_SCALE * g[f]) + be[f];
        val = fmaxf(val, 0.f);
    }
    out[v * 128 + f] = val;
}

// ---------------------------------------------------------------------------
// Output layer: tiny GEMM (HID->2) then aggregation over 2 features.
// ---------------------------------------------------------------------------
__global__ __launch_bounds__(256) void k_gemm_out(
    const float* __restrict__ H,
    const float* __restrict__ Wl, const float* __restrict__ bl,
    const float* __restrict__ Wr, const float* __restrict__ br,
    float* __restrict__ Cl, float* __restrict__ Cr)
{
    int idx = blockIdx.x * 256 + threadIdx.x;
    if (idx >= GN * 2) return;
    int v = idx >> 1, j = idx & 1;
    const float* h = H + (size_t)v * 128;
    float al = 0.f, ar = 0.f;
    #pragma unroll 8
    for (int k = 0; k < 128; ++k) {
        float hv = h[k];
        al = fmaf(hv, Wl[k * 2 + j], al);
        ar = fmaf(hv, Wr[k * 2 + j], ar);
    }
    Cl[idx] = al + bl[j];
    Cr[idx] = ar + br[j];
}

__global__ __launch_bounds__(256) void k_agg_out(
    const float* __restrict__ hl2, const float* __restrict__ hr2,
    const int* __restrict__ adj, const int* __restrict__ fill,
    float* __restrict__ out)
{
    int idx = blockIdx.x * 256 + threadIdx.x;
    if (idx >= GN * 2) return;
    int v = idx >> 1, j = idx & 1;
    int cnt = fill[v];
    int d = min(cnt, MAXD);
    const int* ap = adj + v * MAXD;

    float total = 0.f;
    float s0 = INFINITY, s1 = INFINITY, s2 = INFINITY, s3 = INFINITY;
    float l0 = -INFINITY, l1 = -INFINITY, l2 = -INFINITY, l3 = -INFINITY;
    for (int i = 0; i < d; ++i) {
        float x = hl2[ap[i] * 2 + j];
        total += x;
        float a = x;
        float t0 = fminf(s0, a); a = fmaxf(s0, a); s0 = t0;
        float t1 = fminf(s1, a); a = fmaxf(s1, a); s1 = t1;
        float t2 = fminf(s2, a); a = fmaxf(s2, a); s2 = t2;
        s3 = fminf(s3, a);
        float b = x;
        float u0 = fmaxf(l0, b); b = fminf(l0, b); l0 = u0;
        float u1 = fmaxf(l1, b); b = fminf(l1, b); l1 = u1;
        float u2 = fmaxf(l2, b); b = fminf(l2, b); l2 = u2;
        l3 = fmaxf(l3, b);
    }

    int t = (int)floorf((float)cnt * 0.1f);
    if (t < 1) t = 1;
    int tcnt = cnt - 2 * t;
    bool use_trim = (cnt >= 5) && (tcnt > 0);
    float dd = (float)cnt;
    float res;
    if (use_trim) {
        int tt = min(t, 4);
        float bot = s0, top = l0;
        if (tt > 1) { bot += s1; top += l1; }
        if (tt > 2) { bot += s2; top += l2; }
        if (tt > 3) { bot += s3; top += l3; }
        res = (total - bot - top) / (dd * (float)tcnt);
    } else {
        res = total / (dd * dd);
    }
    out[idx] = res + hr2[idx];
}

// ---------------------------------------------------------------------------
extern "C" void kernel_launch(void* const* d_in, const int* in_sizes, int n_in,
                              void* d_out, int out_size, void* d_ws, size_t ws_size,
                              hipStream_t stream)
{
    const float* x   = (const float*)d_in[0];
    const int*   ei  = (const int*)d_in[1];
    const int    E   = in_sizes[1] / 2;
    const float* Wl0 = (const float*)d_in[2];
    const float* bl0 = (const float*)d_in[3];
    const float* Wr0 = (const float*)d_in[4];
    const float* br0 = (const float*)d_in[5];
    const float* g0  = (const float*)d_in[6];
    const float* be0 = (const float*)d_in[7];
    const float* Wl1 = (const float*)d_in[8];
    const float* bl1 = (const float*)d_in[9];
    const float* Wr1 = (const float*)d_in[10];
    const float* br1 = (const float*)d_in[11];
    const float* g1  = (const float*)d_in[12];
    const float* be1 = (const float*)d_in[13];
    const float* Wl2 = (const float*)d_in[14];
    const float* bl2 = (const float*)d_in[15];
    const float* Wr2 = (const float*)d_in[16];
    const float* br2 = (const float*)d_in[17];
    float* out = (float*)d_out;

    char* w = (char*)d_ws;
    int*   adj  = (int*)w;   w += (size_t)GN * MAXD * 4;
    int*   fill = (int*)w;   w += (size_t)GN * 4;
    float* hl   = (float*)w; w += (size_t)GN * 128 * 4;
    float* hr   = (float*)w; w += (size_t)GN * 128 * 4;
    float* hb   = (float*)w; w += (size_t)GN * 128 * 4;
    float* hl2  = (float*)w; w += (size_t)GN * 2 * 4;
    float* hr2  = (float*)w; w += (size_t)GN * 2 * 4;

    k_init <<<GN / 256, 256, 0, stream>>>(adj, fill);
    k_build<<<(E + 255) / 256, 256, 0, stream>>>(ei, ei + E, adj, fill, E);

    // layer 0
    k_gemm_dual<<<GN / 64, 256, 0, stream>>>(x, Wl0, bl0, Wr0, br0, hl, hr);
    k_agg<<<GN, 128, 0, stream>>>(hl, hr, adj, fill, g0, be0, hb, 1);
    // layer 1
    k_gemm_dual<<<GN / 64, 256, 0, stream>>>(hb, Wl1, bl1, Wr1, br1, hl, hr);
    k_agg<<<GN, 128, 0, stream>>>(hl, hr, adj, fill, g1, be1, hb, 1);
    // layer 2 (output dim 2)
    k_gemm_out<<<(GN * 2 + 255) / 256, 256, 0, stream>>>(hb, Wl2, bl2, Wr2, br2, hl2, hr2);
    k_agg_out<<<(GN * 2 + 255) / 256, 256, 0, stream>>>(hl2, hr2, adj, fill, out);
}

// Round 3
// 210.043 us; speedup vs baseline: 1.0627x; 1.0627x over previous
//
#include <hip/hip_runtime.h>
#include <hip/hip_bf16.h>
#include <math.h>

#define GN    16384
#define HID   128
#define MAXD  48
#define BN_SCALE 0.9999950000374998f   // 1/sqrt(1+1e-5)

typedef __attribute__((ext_vector_type(8))) short short8;
typedef __attribute__((ext_vector_type(4))) float f32x4;

// ---- bf16 helpers (RN) ----
__device__ inline short f2bf(float x) {
    unsigned u = __float_as_uint(x);
    unsigned r = (u + 0x7fffu + ((u >> 16) & 1u)) >> 16;
    return (short)r;
}
__device__ inline float bf2f(short s) {
    return __uint_as_float(((unsigned)(unsigned short)s) << 16);
}

// ---------------------------------------------------------------------------
// k_prep: node init (fill/adj self loop) + W split into MFMA-fragment-order
// layout. W5 granule (16B = short8) holds one B-fragment (8 bf16) for
// (split, ks, ntile, lane): elem j -> W[k = ks*32 + (j>>2)*16 + q*4 + (j&3)]
// [n = nt*16 + r], lane l = q*16+r. split0 = hi, split1 = lo.
// Per layer: 8192 granules = 128KB. 2 layers -> 16384 granules = 16384 threads.
// ---------------------------------------------------------------------------
__global__ __launch_bounds__(256) void k_prep(
    int* __restrict__ adj, int* __restrict__ fill,
    const float* __restrict__ Wl0, const float* __restrict__ Wr0,
    const float* __restrict__ Wl1, const float* __restrict__ Wr1,
    short* __restrict__ W5)
{
    int t = blockIdx.x * 256 + threadIdx.x;   // 0..16383
    // node init
    fill[t] = 1;
    adj[t * MAXD] = t;

    // W granule
    int layer = t >> 13;
    int g     = t & 8191;
    int split = (g >> 12) & 1;
    int ks    = (g >> 10) & 3;
    int nt    = (g >> 6) & 15;
    int l     = g & 63;
    int q = l >> 4, r = l & 15;
    int n = nt * 16 + r;
    const float* Wl = layer ? Wl1 : Wl0;
    const float* Wr = layer ? Wr1 : Wr0;
    const float* W  = (n < 128) ? Wl : Wr;
    int ncol = (n < 128) ? n : (n - 128);

    short8 out;
    #pragma unroll
    for (int j = 0; j < 8; ++j) {
        int k = ks * 32 + (j >> 2) * 16 + q * 4 + (j & 3);
        float wv = W[k * 128 + ncol];
        short hi = f2bf(wv);
        short val = split ? f2bf(wv - bf2f(hi)) : hi;
        out[j] = val;
    }
    *reinterpret_cast<short8*>(W5 + ((size_t)layer * 8192 + g) * 8) = out;
}

// ---------------------------------------------------------------------------
__global__ __launch_bounds__(256) void k_build(const int* __restrict__ src,
                                               const int* __restrict__ dst,
                                               int* __restrict__ adj,
                                               int* __restrict__ fill, int E) {
    int e = blockIdx.x * 256 + threadIdx.x;
    if (e < E) {
        int dv = dst[e];
        int slot = atomicAdd(&fill[dv], 1);
        if (slot < MAXD) adj[dv * MAXD + slot] = src[e];
    }
}

// ---------------------------------------------------------------------------
// MFMA GEMM: C[16384][256] = X[16384][128] @ [Wl | Wr] + [bl | br]
// split-bf16: X = xhi + xlo, W = whi + wlo; acc += xhi*whi + xhi*wlo + xlo*whi
// Block: 256 thr = 4 waves; wave w owns rows w*16..+15 of a 64-row tile.
// B fragments read straight from global W5 (L2-resident, stride-1 per wave).
// ---------------------------------------------------------------------------
__global__ __launch_bounds__(256, 1) void k_gemm(
    const float* __restrict__ X, const short* __restrict__ W5,
    const float* __restrict__ bl, const float* __restrict__ br,
    float* __restrict__ C)
{
    const int tid = threadIdx.x;
    const int w = tid >> 6, l = tid & 63;
    const int q = l >> 4, r = l & 15;
    const int rowA = blockIdx.x * 64 + w * 16 + r;

    // Load + split A row (this lane's row, k = 16h + 4q + j)
    short ahi[8][4], alo[8][4];
    const float4* xp = reinterpret_cast<const float4*>(X + (size_t)rowA * 128);
    #pragma unroll
    for (int h = 0; h < 8; ++h) {
        float4 v = xp[h * 4 + q];
        float xv[4] = {v.x, v.y, v.z, v.w};
        #pragma unroll
        for (int j = 0; j < 4; ++j) {
            short hi = f2bf(xv[j]);
            ahi[h][j] = hi;
            alo[h][j] = f2bf(xv[j] - bf2f(hi));
        }
    }

    f32x4 acc[16];
    #pragma unroll
    for (int nt = 0; nt < 16; ++nt) {
        int col = nt * 16 + r;
        float b = (nt < 8) ? bl[col] : br[col - 128];
        acc[nt] = (f32x4){b, b, b, b};
    }

    #pragma unroll
    for (int ks = 0; ks < 4; ++ks) {
        short8 Ahi, Alo;
        #pragma unroll
        for (int j = 0; j < 4; ++j) {
            Ahi[j] = ahi[2 * ks][j];     Ahi[j + 4] = ahi[2 * ks + 1][j];
            Alo[j] = alo[2 * ks][j];     Alo[j + 4] = alo[2 * ks + 1][j];
        }
        #pragma unroll
        for (int nt = 0; nt < 16; ++nt) {
            short8 Bhi = *reinterpret_cast<const short8*>(
                W5 + ((size_t)(ks * 16 + nt) * 64 + l) * 8);
            short8 Blo = *reinterpret_cast<const short8*>(
                W5 + ((size_t)((4 + ks) * 16 + nt) * 64 + l) * 8);
            acc[nt] = __builtin_amdgcn_mfma_f32_16x16x32_bf16(Ahi, Bhi, acc[nt], 0, 0, 0);
            acc[nt] = __builtin_amdgcn_mfma_f32_16x16x32_bf16(Ahi, Blo, acc[nt], 0, 0, 0);
            acc[nt] = __builtin_amdgcn_mfma_f32_16x16x32_bf16(Alo, Bhi, acc[nt], 0, 0, 0);
        }
    }

    // store: D reg j -> row 4q+j (of wave tile), col nt*16+r
    const int rb = blockIdx.x * 64 + w * 16 + 4 * q;
    #pragma unroll
    for (int nt = 0; nt < 16; ++nt) {
        int col = nt * 16 + r;
        #pragma unroll
        for (int j = 0; j < 4; ++j)
            C[(size_t)(rb + j) * 256 + col] = acc[nt][j];
    }
}

// ---------------------------------------------------------------------------
// Aggregation: one wave per node, lane handles features 2l, 2l+1 (float2).
// hl = C[:, 0:128], hr = C[:, 128:256]. Writes hb fp32.
// ---------------------------------------------------------------------------
struct F2 { float x, y; };
__device__ inline F2 f2min(F2 a, F2 b) { return {fminf(a.x, b.x), fminf(a.y, b.y)}; }
__device__ inline F2 f2max(F2 a, F2 b) { return {fmaxf(a.x, b.x), fmaxf(a.y, b.y)}; }

__global__ __launch_bounds__(256) void k_agg(
    const float* __restrict__ C,
    const int* __restrict__ adj, const int* __restrict__ fill,
    const float* __restrict__ g, const float* __restrict__ be,
    float* __restrict__ hb)
{
    __shared__ int sadj[4][MAXD];
    const int tid = threadIdx.x, w = tid >> 6, l = tid & 63;
    const int v = blockIdx.x * 4 + w;
    const int cnt = fill[v];
    const int d = min(cnt, MAXD);
    if (l < d) sadj[w][l] = adj[v * MAXD + l] * 256;
    __syncthreads();

    const int f2 = l * 2;
    F2 tot = {0.f, 0.f};
    F2 s0 = { INFINITY,  INFINITY}, s1 = s0, s2 = s0, s3 = s0;
    F2 l0 = {-INFINITY, -INFINITY}, l1 = l0, l2 = l0, l3 = l0;

    if (cnt < 20) {   // t == 1: min/max only (wave-uniform branch)
        for (int i = 0; i < d; ++i) {
            const float2 xv = *reinterpret_cast<const float2*>(C + sadj[w][i] + f2);
            F2 x = {xv.x, xv.y};
            tot.x += x.x; tot.y += x.y;
            s0 = f2min(s0, x);
            l0 = f2max(l0, x);
        }
    } else {          // t in [2,4]: 4-deep branchless trackers
        for (int i = 0; i < d; ++i) {
            const float2 xv = *reinterpret_cast<const float2*>(C + sadj[w][i] + f2);
            F2 x = {xv.x, xv.y};
            tot.x += x.x; tot.y += x.y;
            F2 a = x;
            F2 t0 = f2min(s0, a); a = f2max(s0, a); s0 = t0;
            F2 t1 = f2min(s1, a); a = f2max(s1, a); s1 = t1;
            F2 t2 = f2min(s2, a); a = f2max(s2, a); s2 = t2;
            s3 = f2min(s3, a);
            F2 b = x;
            F2 u0 = f2max(l0, b); b = f2min(l0, b); l0 = u0;
            F2 u1 = f2max(l1, b); b = f2min(l1, b); l1 = u1;
            F2 u2 = f2max(l2, b); b = f2min(l2, b); l2 = u2;
            l3 = f2max(l3, b);
        }
    }

    int t = (int)floorf((float)cnt * 0.1f);
    if (t < 1) t = 1;
    int tcnt = cnt - 2 * t;
    bool use_trim = (cnt >= 5) && (tcnt > 0);
    float dd = (float)cnt;
    F2 res;
    if (use_trim) {
        int tt = min(t, 4);
        F2 bot = s0, top = l0;
        if (tt > 1) { bot.x += s1.x; bot.y += s1.y; top.x += l1.x; top.y += l1.y; }
        if (tt > 2) { bot.x += s2.x; bot.y += s2.y; top.x += l2.x; top.y += l2.y; }
        if (tt > 3) { bot.x += s3.x; bot.y += s3.y; top.x += l3.x; top.y += l3.y; }
        float inv = 1.0f / (dd * (float)tcnt);
        res.x = (tot.x - bot.x - top.x) * inv;
        res.y = (tot.y - bot.y - top.y) * inv;
    } else {
        float inv = 1.0f / (dd * dd);
        res.x = tot.x * inv;
        res.y = tot.y * inv;
    }

    const float2 hrv = *reinterpret_cast<const float2*>(C + (size_t)v * 256 + 128 + f2);
    float v0 = res.x + hrv.x;
    float v1 = res.y + hrv.y;
    v0 = fmaxf(v0 * (BN_SCALE * g[f2])     + be[f2],     0.f);
    v1 = fmaxf(v1 * (BN_SCALE * g[f2 + 1]) + be[f2 + 1], 0.f);
    float2 o = {v0, v1};
    *reinterpret_cast<float2*>(hb + (size_t)v * 128 + f2) = o;
}

// ---------------------------------------------------------------------------
// Output layer: HID->2 GEMM (one node per thread, float4 + scalar W via SGPR)
// ---------------------------------------------------------------------------
__global__ __launch_bounds__(256) void k_gemm_out(
    const float* __restrict__ H,
    const float* __restrict__ Wl, const float* __restrict__ bl,
    const float* __restrict__ Wr, const float* __restrict__ br,
    float* __restrict__ Cl, float* __restrict__ Cr)
{
    int v = blockIdx.x * 256 + threadIdx.x;
    const float4* h = reinterpret_cast<const float4*>(H + (size_t)v * 128);
    float a0 = 0.f, a1 = 0.f, r0 = 0.f, r1 = 0.f;
    #pragma unroll
    for (int k4 = 0; k4 < 32; ++k4) {
        float4 hv = h[k4];
        float xs[4] = {hv.x, hv.y, hv.z, hv.w};
        #pragma unroll
        for (int c = 0; c < 4; ++c) {
            int k = 4 * k4 + c;
            a0 = fmaf(xs[c], Wl[k * 2 + 0], a0);
            a1 = fmaf(xs[c], Wl[k * 2 + 1], a1);
            r0 = fmaf(xs[c], Wr[k * 2 + 0], r0);
            r1 = fmaf(xs[c], Wr[k * 2 + 1], r1);
        }
    }
    Cl[v * 2 + 0] = a0 + bl[0];
    Cl[v * 2 + 1] = a1 + bl[1];
    Cr[v * 2 + 0] = r0 + br[0];
    Cr[v * 2 + 1] = r1 + br[1];
}

__global__ __launch_bounds__(256) void k_agg_out(
    const float* __restrict__ hl2, const float* __restrict__ hr2,
    const int* __restrict__ adj, const int* __restrict__ fill,
    float* __restrict__ out)
{
    int idx = blockIdx.x * 256 + threadIdx.x;
    int v = idx >> 1, j = idx & 1;
    int cnt = fill[v];
    int d = min(cnt, MAXD);
    const int* ap = adj + v * MAXD;

    float total = 0.f;
    float s0 = INFINITY, s1 = INFINITY, s2 = INFINITY, s3 = INFINITY;
    float l0 = -INFINITY, l1 = -INFINITY, l2 = -INFINITY, l3 = -INFINITY;
    for (int i = 0; i < d; ++i) {
        float x = hl2[ap[i] * 2 + j];
        total += x;
        float a = x;
        float t0 = fminf(s0, a); a = fmaxf(s0, a); s0 = t0;
        float t1 = fminf(s1, a); a = fmaxf(s1, a); s1 = t1;
        float t2 = fminf(s2, a); a = fmaxf(s2, a); s2 = t2;
        s3 = fminf(s3, a);
        float b = x;
        float u0 = fmaxf(l0, b); b = fminf(l0, b); l0 = u0;
        float u1 = fmaxf(l1, b); b = fminf(l1, b); l1 = u1;
        float u2 = fmaxf(l2, b); b = fminf(l2, b); l2 = u2;
        l3 = fmaxf(l3, b);
    }

    int t = (int)floorf((float)cnt * 0.1f);
    if (t < 1) t = 1;
    int tcnt = cnt - 2 * t;
    bool use_trim = (cnt >= 5) && (tcnt > 0);
    float dd = (float)cnt;
    float res;
    if (use_trim) {
        int tt = min(t, 4);
        float bot = s0, top = l0;
        if (tt > 1) { bot += s1; top += l1; }
        if (tt > 2) { bot += s2; top += l2; }
        if (tt > 3) { bot += s3; top += l3; }
        res = (total - bot - top) / (dd * (float)tcnt);
    } else {
        res = total / (dd * dd);
    }
    out[idx] = res + hr2[idx];
}

// ---------------------------------------------------------------------------
extern "C" void kernel_launch(void* const* d_in, const int* in_sizes, int n_in,
                              void* d_out, int out_size, void* d_ws, size_t ws_size,
                              hipStream_t stream)
{
    const float* x   = (const float*)d_in[0];
    const int*   ei  = (const int*)d_in[1];
    const int    E   = in_sizes[1] / 2;
    const float* Wl0 = (const float*)d_in[2];
    const float* bl0 = (const float*)d_in[3];
    const float* Wr0 = (const float*)d_in[4];
    const float* br0 = (const float*)d_in[5];
    const float* g0  = (const float*)d_in[6];
    const float* be0 = (const float*)d_in[7];
    const float* Wl1 = (const float*)d_in[8];
    const float* bl1 = (const float*)d_in[9];
    const float* Wr1 = (const float*)d_in[10];
    const float* br1 = (const float*)d_in[11];
    const float* g1  = (const float*)d_in[12];
    const float* be1 = (const float*)d_in[13];
    const float* Wl2 = (const float*)d_in[14];
    const float* bl2 = (const float*)d_in[15];
    const float* Wr2 = (const float*)d_in[16];
    const float* br2 = (const float*)d_in[17];
    float* out = (float*)d_out;

    char* w = (char*)d_ws;
    int*   adj  = (int*)w;    w += (size_t)GN * MAXD * 4;
    int*   fill = (int*)w;    w += (size_t)GN * 4;
    float* C    = (float*)w;  w += (size_t)GN * 256 * 4;
    float* hb   = (float*)w;  w += (size_t)GN * 128 * 4;
    short* W5   = (short*)w;  w += (size_t)2 * 8192 * 16;
    float* hl2  = (float*)w;  w += (size_t)GN * 2 * 4;
    float* hr2  = (float*)w;  w += (size_t)GN * 2 * 4;

    k_prep <<<GN / 256, 256, 0, stream>>>(adj, fill, Wl0, Wr0, Wl1, Wr1, W5);
    k_build<<<(E + 255) / 256, 256, 0, stream>>>(ei, ei + E, adj, fill, E);

    // layer 0
    k_gemm<<<GN / 64, 256, 0, stream>>>(x, W5, bl0, br0, C);
    k_agg <<<GN / 4, 256, 0, stream>>>(C, adj, fill, g0, be0, hb);
    // layer 1
    k_gemm<<<GN / 64, 256, 0, stream>>>(hb, W5 + (size_t)8192 * 8, bl1, br1, C);
    k_agg <<<GN / 4, 256, 0, stream>>>(C, adj, fill, g1, be1, hb);
    // layer 2 (output dim 2)
    k_gemm_out<<<GN / 256, 256, 0, stream>>>(hb, Wl2, bl2, Wr2, br2, hl2, hr2);
    k_agg_out<<<GN * 2 / 256, 256, 0, stream>>>(hl2, hr2, adj, fill, out);
}

// Round 4
// 200.155 us; speedup vs baseline: 1.1151x; 1.0494x over previous
//
#include <hip/hip_runtime.h>
#include <hip/hip_bf16.h>
#include <hip/hip_fp16.h>
#include <math.h>

#define GN    16384
#define MAXD  48
#define BN_SCALE 0.9999950000374998f   // 1/sqrt(1+1e-5)

typedef __attribute__((ext_vector_type(8))) short short8;
typedef __attribute__((ext_vector_type(4))) float f32x4;
typedef _Float16 __attribute__((ext_vector_type(2))) h2v;

__device__ inline short f2bf(float x) {
    unsigned u = __float_as_uint(x);
    return (short)((u + 0x7fffu + ((u >> 16) & 1u)) >> 16);
}
__device__ inline float bf2f(short s) {
    return __uint_as_float(((unsigned)(unsigned short)s) << 16);
}

// ---------------------------------------------------------------------------
// One fused setup kernel (after memset(fill,0)): edge append + self-loop
// append (both atomic, order-invariant) + W split/swizzle into MFMA B-layout.
// W5 granule (16B) for (layer, split, ks, nt, lane): elem j ->
//   W[k = ks*32 + (j>>2)*16 + q*4 + (j&3)][n = nt*16 + r], lane l = q*16+r.
// ---------------------------------------------------------------------------
__global__ __launch_bounds__(256) void k_build(
    const int* __restrict__ src, const int* __restrict__ dst, int E,
    int* __restrict__ adj, int* __restrict__ fill,
    const float* __restrict__ Wl0, const float* __restrict__ Wr0,
    const float* __restrict__ Wl1, const float* __restrict__ Wr1,
    short* __restrict__ W5)
{
    int idx = blockIdx.x * 256 + threadIdx.x;
    if (idx < E) {
        int dv = dst[idx];
        int slot = atomicAdd(&fill[dv], 1);
        if (slot < MAXD) adj[dv * MAXD + slot] = src[idx];   // drop overflow
        return;
    }
    idx -= E;
    if (idx < GN) {          // self loop
        int slot = atomicAdd(&fill[idx], 1);
        if (slot < MAXD) adj[idx * MAXD + slot] = idx;
        return;
    }
    idx -= GN;
    if (idx >= 2 * 8192) return;   // W granules: 2 layers x 8192
    int layer = idx >> 13;
    int g     = idx & 8191;
    int split = (g >> 12) & 1;
    int ks    = (g >> 10) & 3;
    int nt    = (g >> 6) & 15;
    int l     = g & 63;
    int q = l >> 4, r = l & 15;
    int n = nt * 16 + r;
    const float* W = (n < 128) ? (layer ? Wl1 : Wl0) : (layer ? Wr1 : Wr0);
    int ncol = n & 127;
    short8 out;
    #pragma unroll
    for (int j = 0; j < 8; ++j) {
        int k = ks * 32 + (j >> 2) * 16 + q * 4 + (j & 3);
        float wv = W[k * 128 + ncol];
        short hi = f2bf(wv);
        out[j] = split ? f2bf(wv - bf2f(hi)) : hi;
    }
    *reinterpret_cast<short8*>(W5 + ((size_t)layer * 8192 + g) * 8) = out;
}

// ---------------------------------------------------------------------------
// MFMA GEMM: HL[16384][128](fp16) = X@Wl + bl ; HR[16384][128](fp32) = X@Wr + br
// split-bf16 (3 MFMA per fragment pair). Block = 32 rows; wave w:
// rows base+(w&1)*16, cols (w>>1)*128..+127. 512 blocks, 2 waves/SIMD.
// B fragments read straight from L2-resident W5.
// ---------------------------------------------------------------------------
__global__ __launch_bounds__(256, 2) void k_gemm(
    const float* __restrict__ X, const short* __restrict__ W5,
    const float* __restrict__ bl, const float* __restrict__ br,
    _Float16* __restrict__ HL, float* __restrict__ HR)
{
    const int tid = threadIdx.x;
    const int w = tid >> 6, l = tid & 63;
    const int q = l >> 4, r = l & 15;
    const int half = w & 1, nhalf = w >> 1;
    const int rowA = blockIdx.x * 32 + half * 16 + r;

    // Load + split A row into per-ks fragments (k = 32ks + 16hk + 4q + j)
    short8 Ahi[4], Alo[4];
    const float4* xp = reinterpret_cast<const float4*>(X + (size_t)rowA * 128);
    #pragma unroll
    for (int h = 0; h < 8; ++h) {
        float4 v = xp[h * 4 + q];
        float xv[4] = {v.x, v.y, v.z, v.w};
        int ks = h >> 1, hk = h & 1;
        #pragma unroll
        for (int j = 0; j < 4; ++j) {
            short hi = f2bf(xv[j]);
            Ahi[ks][hk * 4 + j] = hi;
            Alo[ks][hk * 4 + j] = f2bf(xv[j] - bf2f(hi));
        }
    }

    const float* bias = nhalf ? br : bl;
    f32x4 acc[8];
    #pragma unroll
    for (int nt = 0; nt < 8; ++nt) {
        float b = bias[nt * 16 + r];
        acc[nt] = (f32x4){b, b, b, b};
    }

    #pragma unroll
    for (int ks = 0; ks < 4; ++ks) {
        #pragma unroll
        for (int nt = 0; nt < 8; ++nt) {
            int ntg = nhalf * 8 + nt;
            short8 Bhi = *reinterpret_cast<const short8*>(
                W5 + ((size_t)((ks) * 16 + ntg) * 64 + l) * 8);
            short8 Blo = *reinterpret_cast<const short8*>(
                W5 + ((size_t)((4 + ks) * 16 + ntg) * 64 + l) * 8);
            acc[nt] = __builtin_amdgcn_mfma_f32_16x16x32_bf16(Ahi[ks], Bhi, acc[nt], 0, 0, 0);
            acc[nt] = __builtin_amdgcn_mfma_f32_16x16x32_bf16(Ahi[ks], Blo, acc[nt], 0, 0, 0);
            acc[nt] = __builtin_amdgcn_mfma_f32_16x16x32_bf16(Alo[ks], Bhi, acc[nt], 0, 0, 0);
        }
    }

    // D reg j -> row rb+j, col nt*16+r
    const int rb = blockIdx.x * 32 + half * 16 + 4 * q;
    if (nhalf == 0) {
        #pragma unroll
        for (int nt = 0; nt < 8; ++nt) {
            int c = nt * 16 + r;
            #pragma unroll
            for (int j = 0; j < 4; ++j)
                HL[(size_t)(rb + j) * 128 + c] = (_Float16)acc[nt][j];
        }
    } else {
        #pragma unroll
        for (int nt = 0; nt < 8; ++nt) {
            int c = nt * 16 + r;
            #pragma unroll
            for (int j = 0; j < 4; ++j)
                HR[(size_t)(rb + j) * 128 + c] = acc[nt][j];
        }
    }
}

// ---------------------------------------------------------------------------
// Trimmed-mean aggregation. One wave per node; lane l owns features 2l,2l+1.
// HL gathers are fp16 (4 MB buffer -> per-XCD L2 resident).
// ---------------------------------------------------------------------------
struct F2 { float x, y; };
__device__ inline F2 f2min(F2 a, F2 b) { return {fminf(a.x, b.x), fminf(a.y, b.y)}; }
__device__ inline F2 f2max(F2 a, F2 b) { return {fmaxf(a.x, b.x), fmaxf(a.y, b.y)}; }

__global__ __launch_bounds__(256) void k_agg(
    const _Float16* __restrict__ HL, const float* __restrict__ HR,
    const int* __restrict__ adj, const int* __restrict__ fill,
    const float* __restrict__ g, const float* __restrict__ be,
    float* __restrict__ hb)
{
    __shared__ int sadj[4][MAXD];
    const int tid = threadIdx.x, w = tid >> 6, l = tid & 63;
    const int v = blockIdx.x * 4 + w;
    const int cnt = fill[v];
    const int d = min(cnt, MAXD);
    if (l < d) sadj[w][l] = adj[v * MAXD + l] * 128;
    __syncthreads();

    const int f2i = l * 2;
    F2 tot = {0.f, 0.f};
    F2 s0 = { INFINITY,  INFINITY}, s1 = s0, s2 = s0, s3 = s0;
    F2 l0 = {-INFINITY, -INFINITY}, l1 = l0, l2 = l0, l3 = l0;

    if (cnt < 20) {   // t == 1: min/max only (wave-uniform)
        for (int i = 0; i < d; ++i) {
            h2v hv = *reinterpret_cast<const h2v*>(HL + sadj[w][i] + f2i);
            F2 x = {(float)hv[0], (float)hv[1]};
            tot.x += x.x; tot.y += x.y;
            s0 = f2min(s0, x);
            l0 = f2max(l0, x);
        }
    } else {          // t in [2,4]
        for (int i = 0; i < d; ++i) {
            h2v hv = *reinterpret_cast<const h2v*>(HL + sadj[w][i] + f2i);
            F2 x = {(float)hv[0], (float)hv[1]};
            tot.x += x.x; tot.y += x.y;
            F2 a = x;
            F2 t0 = f2min(s0, a); a = f2max(s0, a); s0 = t0;
            F2 t1 = f2min(s1, a); a = f2max(s1, a); s1 = t1;
            F2 t2 = f2min(s2, a); a = f2max(s2, a); s2 = t2;
            s3 = f2min(s3, a);
            F2 b = x;
            F2 u0 = f2max(l0, b); b = f2min(l0, b); l0 = u0;
            F2 u1 = f2max(l1, b); b = f2min(l1, b); l1 = u1;
            F2 u2 = f2max(l2, b); b = f2min(l2, b); l2 = u2;
            l3 = f2max(l3, b);
        }
    }

    int t = (int)floorf((float)cnt * 0.1f);
    if (t < 1) t = 1;
    int tcnt = cnt - 2 * t;
    bool use_trim = (cnt >= 5) && (tcnt > 0);
    float dd = (float)cnt;
    F2 res;
    if (use_trim) {
        int tt = min(t, 4);
        F2 bot = s0, top = l0;
        if (tt > 1) { bot.x += s1.x; bot.y += s1.y; top.x += l1.x; top.y += l1.y; }
        if (tt > 2) { bot.x += s2.x; bot.y += s2.y; top.x += l2.x; top.y += l2.y; }
        if (tt > 3) { bot.x += s3.x; bot.y += s3.y; top.x += l3.x; top.y += l3.y; }
        float inv = 1.0f / (dd * (float)tcnt);
        res.x = (tot.x - bot.x - top.x) * inv;
        res.y = (tot.y - bot.y - top.y) * inv;
    } else {
        float inv = 1.0f / (dd * dd);
        res.x = tot.x * inv;
        res.y = tot.y * inv;
    }

    const float2 hrv = *reinterpret_cast<const float2*>(HR + (size_t)v * 128 + f2i);
    float v0 = fmaxf((res.x + hrv.x) * (BN_SCALE * g[f2i])     + be[f2i],     0.f);
    float v1 = fmaxf((res.y + hrv.y) * (BN_SCALE * g[f2i + 1]) + be[f2i + 1], 0.f);
    float2 o = {v0, v1};
    *reinterpret_cast<float2*>(hb + (size_t)v * 128 + f2i) = o;
}

// ---------------------------------------------------------------------------
// Output layer: HID->2. Two threads per node (j = 0/1), W via SGPR broadcast.
// ---------------------------------------------------------------------------
__global__ __launch_bounds__(256) void k_gemm_out(
    const float* __restrict__ H,
    const float* __restrict__ Wl, const float* __restrict__ bl,
    const float* __restrict__ Wr, const float* __restrict__ br,
    float* __restrict__ hl2, float* __restrict__ hr2)
{
    int idx = blockIdx.x * 256 + threadIdx.x;   // < 2*GN
    int v = idx >> 1, j = idx & 1;
    const float4* h = reinterpret_cast<const float4*>(H + (size_t)v * 128);
    float a = 0.f, rr = 0.f;
    #pragma unroll
    for (int k4 = 0; k4 < 32; ++k4) {
        float4 hv = h[k4];
        float xs[4] = {hv.x, hv.y, hv.z, hv.w};
        #pragma unroll
        for (int c = 0; c < 4; ++c) {
            int k = 4 * k4 + c;
            a  = fmaf(xs[c], Wl[k * 2 + j], a);
            rr = fmaf(xs[c], Wr[k * 2 + j], rr);
        }
    }
    hl2[idx] = a + bl[j];
    hr2[idx] = rr + br[j];
}

__global__ __launch_bounds__(256) void k_agg_out(
    const float* __restrict__ hl2, const float* __restrict__ hr2,
    const int* __restrict__ adj, const int* __restrict__ fill,
    float* __restrict__ out)
{
    int idx = blockIdx.x * 256 + threadIdx.x;
    int v = idx >> 1, j = idx & 1;
    int cnt = fill[v];
    int d = min(cnt, MAXD);
    const int* ap = adj + v * MAXD;

    float total = 0.f;
    float s0 = INFINITY, s1 = INFINITY, s2 = INFINITY, s3 = INFINITY;
    float l0 = -INFINITY, l1 = -INFINITY, l2 = -INFINITY, l3 = -INFINITY;
    for (int i = 0; i < d; ++i) {
        float x = hl2[ap[i] * 2 + j];
        total += x;
        float a = x;
        float t0 = fminf(s0, a); a = fmaxf(s0, a); s0 = t0;
        float t1 = fminf(s1, a); a = fmaxf(s1, a); s1 = t1;
        float t2 = fminf(s2, a); a = fmaxf(s2, a); s2 = t2;
        s3 = fminf(s3, a);
        float b = x;
        float u0 = fmaxf(l0, b); b = fminf(l0, b); l0 = u0;
        float u1 = fmaxf(l1, b); b = fminf(l1, b); l1 = u1;
        float u2 = fmaxf(l2, b); b = fminf(l2, b); l2 = u2;
        l3 = fmaxf(l3, b);
    }

    int t = (int)floorf((float)cnt * 0.1f);
    if (t < 1) t = 1;
    int tcnt = cnt - 2 * t;
    bool use_trim = (cnt >= 5) && (tcnt > 0);
    float dd = (float)cnt;
    float res;
    if (use_trim) {
        int tt = min(t, 4);
        float bot = s0, top = l0;
        if (tt > 1) { bot += s1; top += l1; }
        if (tt > 2) { bot += s2; top += l2; }
        if (tt > 3) { bot += s3; top += l3; }
        res = (total - bot - top) / (dd * (float)tcnt);
    } else {
        res = total / (dd * dd);
    }
    out[idx] = res + hr2[idx];
}

// ---------------------------------------------------------------------------
extern "C" void kernel_launch(void* const* d_in, const int* in_sizes, int n_in,
                              void* d_out, int out_size, void* d_ws, size_t ws_size,
                              hipStream_t stream)
{
    const float* x   = (const float*)d_in[0];
    const int*   ei  = (const int*)d_in[1];
    const int    E   = in_sizes[1] / 2;
    const float* Wl0 = (const float*)d_in[2];
    const float* bl0 = (const float*)d_in[3];
    const float* Wr0 = (const float*)d_in[4];
    const float* br0 = (const float*)d_in[5];
    const float* g0  = (const float*)d_in[6];
    const float* be0 = (const float*)d_in[7];
    const float* Wl1 = (const float*)d_in[8];
    const float* bl1 = (const float*)d_in[9];
    const float* Wr1 = (const float*)d_in[10];
    const float* br1 = (const float*)d_in[11];
    const float* g1  = (const float*)d_in[12];
    const float* be1 = (const float*)d_in[13];
    const float* Wl2 = (const float*)d_in[14];
    const float* bl2 = (const float*)d_in[15];
    const float* Wr2 = (const float*)d_in[16];
    const float* br2 = (const float*)d_in[17];
    float* out = (float*)d_out;

    char* w = (char*)d_ws;
    int*      adj  = (int*)w;       w += (size_t)GN * MAXD * 4;
    int*      fill = (int*)w;       w += (size_t)GN * 4;
    _Float16* HL   = (_Float16*)w;  w += (size_t)GN * 128 * 2;
    float*    HR   = (float*)w;     w += (size_t)GN * 128 * 4;
    float*    hb   = (float*)w;     w += (size_t)GN * 128 * 4;
    short*    W5   = (short*)w;     w += (size_t)2 * 8192 * 16;
    float*    hl2  = (float*)w;     w += (size_t)GN * 2 * 4;
    float*    hr2  = (float*)w;     w += (size_t)GN * 2 * 4;

    hipMemsetAsync(fill, 0, (size_t)GN * 4, stream);
    {
        int total = E + GN + 2 * 8192;
        k_build<<<(total + 255) / 256, 256, 0, stream>>>(
            ei, ei + E, E, adj, fill, Wl0, Wr0, Wl1, Wr1, W5);
    }

    // layer 0
    k_gemm<<<GN / 32, 256, 0, stream>>>(x, W5, bl0, br0, HL, HR);
    k_agg <<<GN / 4, 256, 0, stream>>>(HL, HR, adj, fill, g0, be0, hb);
    // layer 1
    k_gemm<<<GN / 32, 256, 0, stream>>>(hb, W5 + (size_t)8192 * 8, bl1, br1, HL, HR);
    k_agg <<<GN / 4, 256, 0, stream>>>(HL, HR, adj, fill, g1, be1, hb);
    // layer 2 (output dim 2)
    k_gemm_out<<<GN * 2 / 256, 256, 0, stream>>>(hb, Wl2, bl2, Wr2, br2, hl2, hr2);
    k_agg_out <<<GN * 2 / 256, 256, 0, stream>>>(hl2, hr2, adj, fill, out);
}